// Round 11
// baseline (43.901 us; speedup 1.0000x reference)
//
#include <hip/hip_runtime.h>

#define NROWS   512
#define THREADS 512
#define PULSE_THR 0.01f

typedef float2 cpx;

__device__ __forceinline__ cpx cadd(cpx a, cpx b){ return make_float2(a.x+b.x, a.y+b.y); }
__device__ __forceinline__ cpx csub(cpx a, cpx b){ return make_float2(a.x-b.x, a.y-b.y); }
__device__ __forceinline__ cpx cmul(cpx a, cpx b){
    return make_float2(fmaf(a.x, b.x, -(a.y*b.y)), fmaf(a.x, b.y, a.y*b.x));
}
__device__ __forceinline__ cpx cmuli(cpx a){ return make_float2(-a.y, a.x); }   // i*a
// e^{2*pi*i*rev} via native v_sin/v_cos (argument in revolutions)
__device__ __forceinline__ cpx twf(float rev){
    return make_float2(__builtin_amdgcn_cosf(rev), __builtin_amdgcn_sinf(rev));
}
// LDS slot swizzle: fold bits 4-11 into 0-3 to spread strided accesses.
// Only bits 0-3 change -> preserves 64-element region disjointness (barrier proof).
__device__ __forceinline__ int slotf(int e){ return e ^ ((e >> 4) & 15) ^ ((e >> 8) & 15); }
// base-8 digit reversal of a 9-bit index (3 digits) — involution
__device__ __forceinline__ int rev3(int t){ return ((t & 7) << 6) | (t & 0x38) | (t >> 6); }

// fast atan2: octant reduction + poly, |err| ~1e-5 rad
__device__ __forceinline__ float fast_atan2(float y, float x){
    float ax = fabsf(x), ay = fabsf(y);
    float mx = fmaxf(ax, ay), mn = fminf(ax, ay);
    float a  = mn * __builtin_amdgcn_rcpf(mx);
    if (mx == 0.0f) a = 0.0f;
    float s = a * a;
    float p = fmaf(s, fmaf(s, fmaf(s, fmaf(s, 0.0208351f, -0.085133f),
                                   0.180141f), -0.3302995f), 0.9998660f);
    p = p * a;
    if (ay > ax)   p = 1.57079632679f - p;
    if (x < 0.0f)  p = 3.14159265359f - p;
    return (y < 0.0f) ? -p : p;
}

// short-chain twiddle set: 3 independent sincos (TRANS pipe) + depth-2 cmuls
__device__ __forceinline__ void twiddle7(float sj_L, cpx* w){
    w[0] = twf(sj_L);                 // w1
    w[1] = twf(2.0f * sj_L);          // w2
    w[3] = twf(4.0f * sj_L);          // w4
    w[2] = cmul(w[0], w[1]);          // w3
    w[4] = cmul(w[0], w[3]);          // w5
    w[5] = cmul(w[1], w[3]);          // w6
    w[6] = cmul(w[2], w[3]);          // w7
}

// 8-point DFT, natural order in/out, W8 = e^{-2pi i/8}  (forward)
__device__ __forceinline__ void dft8_fwd(cpx* x){
    const float S = 0.70710678118654752f;
    cpx a0=cadd(x[0],x[4]), a1=cadd(x[1],x[5]), a2=cadd(x[2],x[6]), a3=cadd(x[3],x[7]);
    cpx b0=csub(x[0],x[4]), b1=csub(x[1],x[5]), b2=csub(x[2],x[6]), b3=csub(x[3],x[7]);
    cpx c0=cadd(a0,a2), c1=csub(a0,a2), c2=cadd(a1,a3), c3=csub(a1,a3);
    x[0]=cadd(c0,c2);
    x[4]=csub(c0,c2);
    x[2]=csub(c1,cmuli(c3));
    x[6]=cadd(c1,cmuli(c3));
    cpx t1 = make_float2(S*(b1.x+b1.y), S*(b1.y-b1.x));    // b1*W8
    cpx t2 = make_float2(b2.y, -b2.x);                     // b2*W8^2 = -i b2
    cpx t3 = make_float2(S*(b3.y-b3.x), -S*(b3.x+b3.y));   // b3*W8^3
    cpx d0=cadd(b0,t2), d1=csub(b0,t2), d2=cadd(t1,t3), d3=csub(t1,t3);
    x[1]=cadd(d0,d2);
    x[5]=csub(d0,d2);
    x[3]=csub(d1,cmuli(d3));
    x[7]=cadd(d1,cmuli(d3));
}
// 8-point inverse DFT (unnormalized), conj twiddles
__device__ __forceinline__ void dft8_inv(cpx* x){
    const float S = 0.70710678118654752f;
    cpx a0=cadd(x[0],x[4]), a1=cadd(x[1],x[5]), a2=cadd(x[2],x[6]), a3=cadd(x[3],x[7]);
    cpx b0=csub(x[0],x[4]), b1=csub(x[1],x[5]), b2=csub(x[2],x[6]), b3=csub(x[3],x[7]);
    cpx c0=cadd(a0,a2), c1=csub(a0,a2), c2=cadd(a1,a3), c3=csub(a1,a3);
    x[0]=cadd(c0,c2);
    x[4]=csub(c0,c2);
    x[2]=cadd(c1,cmuli(c3));
    x[6]=csub(c1,cmuli(c3));
    cpx t1 = make_float2(S*(b1.x-b1.y), S*(b1.y+b1.x));    // b1*conj(W8)
    cpx t2 = make_float2(-b2.y, b2.x);                     // +i b2
    cpx t3 = make_float2(-S*(b3.x+b3.y), S*(b3.x-b3.y));   // b3*conj(W8)^3
    cpx d0=cadd(b0,t2), d1=csub(b0,t2), d2=cadd(t1,t3), d3=csub(t1,t3);
    x[1]=cadd(d0,d2);
    x[5]=csub(d0,d2);
    x[3]=cadd(d1,cmuli(d3));
    x[7]=csub(d1,cmuli(d3));
}

// forward DIF radix-8 LDS stage
template<int L>
__device__ __forceinline__ void fwd_stage8(cpx* sd, int tid){
    constexpr int q = L / 8;
    const int j    = tid & (q - 1);
    const int base = ((tid & ~(q - 1)) << 3) + j;
    cpx v[8];
    #pragma unroll
    for (int m = 0; m < 8; ++m) v[m] = sd[slotf(base + m*q)];
    cpx w[7];
    twiddle7(-(float)j * (1.0f/(float)L), w);
    dft8_fwd(v);
    #pragma unroll
    for (int m = 1; m < 8; ++m) v[m] = cmul(v[m], w[m-1]);
    #pragma unroll
    for (int m = 0; m < 8; ++m) sd[slotf(base + m*q)] = v[m];
}
// inverse DIT radix-8 LDS stage
template<int L>
__device__ __forceinline__ void inv_stage8(cpx* sd, int tid){
    constexpr int q = L / 8;
    const int j    = tid & (q - 1);
    const int base = ((tid & ~(q - 1)) << 3) + j;
    cpx v[8];
    #pragma unroll
    for (int m = 0; m < 8; ++m) v[m] = sd[slotf(base + m*q)];
    cpx w[7];
    twiddle7((float)j * (1.0f/(float)L), w);
    #pragma unroll
    for (int m = 1; m < 8; ++m) v[m] = cmul(v[m], w[m-1]);
    dft8_inv(v);
    #pragma unroll
    for (int m = 0; m < 8; ++m) sd[slotf(base + m*q)] = v[m];
}

// Barrier-elision proof sketch (8 waves x 64 lanes, element regions of sdat):
//  stage<512>: wave w owns exactly [w*512, w*512+512).
//  stage<64>:  thread block [(tid>>3)*64, +64) lies inside wave (tid>>6)'s region.
//  middle own: [8*tid, 8*tid+8) inside the same wave region.
//  => s512->s64, middle-write->inv64, inv64->inv512 are wave-local handoffs
//     (per-wave DS ops in order; cross-wave regions disjoint) — no barrier.
//  Barriers kept: init strided write -> s512; s64 -> middle PARTNER read;
//  middle reads -> writes; inv512 -> final strided read.

__global__ __launch_bounds__(THREADS, 4) void pulse_row_kernel(
    const float* __restrict__ pred,
    const float* __restrict__ label,
    float* __restrict__ mse_per)
{
    __shared__ cpx   sdat[4096];           // 32 KB
    __shared__ int   sred[8][4];
    __shared__ float swsum[8];
    __shared__ int   s_first, s_last;
    __shared__ float s_mean;

    const int row  = blockIdx.x;
    const int tid  = threadIdx.x;
    const int lane = tid & 63;
    const int wid  = tid >> 6;

    const float* lab_r = label + (size_t)row * 16384;
    const float* lab_i = lab_r + 8192;
    const float2* lr2 = (const float2*)lab_r;
    const float2* li2 = (const float2*)lab_i;

    // ---------- Phase 0: load labels in EPILOGUE layout and keep in regs ----------
    // lrv[m]/liv[m] = label float2 pair covering elements n = 2*(tid+512m), +1.
    // Grid caps occupancy at 4 waves/SIMD, which allows up to 128 VGPRs -> the
    // ~32 registers holding the labels across the FFT are occupancy-free.
    float2 lrv[8], liv[8];
    #pragma unroll
    for (int m = 0; m < 8; ++m){
        lrv[m] = lr2[tid + 512*m];
        liv[m] = li2[tid + 512*m];
    }
    int minr = 8192, maxr = -1, mini = 8192, maxi = -1;
    #pragma unroll
    for (int m = 0; m < 8; ++m){
        int n = 2 * (tid + 512*m);
        if (fabsf(lrv[m].x) > PULSE_THR){ minr = min(minr, n);   maxr = max(maxr, n);   }
        if (fabsf(lrv[m].y) > PULSE_THR){ minr = min(minr, n+1); maxr = max(maxr, n+1); }
        if (fabsf(liv[m].x) > PULSE_THR){ mini = min(mini, n);   maxi = max(maxi, n);   }
        if (fabsf(liv[m].y) > PULSE_THR){ mini = min(mini, n+1); maxi = max(maxi, n+1); }
    }
    #pragma unroll
    for (int off = 32; off; off >>= 1){
        minr = min(minr, __shfl_down(minr, off));
        maxr = max(maxr, __shfl_down(maxr, off));
        mini = min(mini, __shfl_down(mini, off));
        maxi = max(maxi, __shfl_down(maxi, off));
    }
    if (lane == 0){ sred[wid][0]=minr; sred[wid][1]=maxr; sred[wid][2]=mini; sred[wid][3]=maxi; }

    // ---------- Load z[t]=x[2t]+i x[2t+1] (kept in regs) + fused fwd L=4096 ----------
    const float2* zin = (const float2*)(pred + (size_t)row * 8192);
    cpx zv[8];
    #pragma unroll
    for (int u = 0; u < 8; ++u) zv[u] = zin[tid + THREADS * u];
    {
        cpx v[8];
        #pragma unroll
        for (int m = 0; m < 8; ++m) v[m] = zv[m];
        cpx w[7];
        twiddle7(-(float)tid * (1.0f/4096.0f), w);
        dft8_fwd(v);
        #pragma unroll
        for (int m = 1; m < 8; ++m) v[m] = cmul(v[m], w[m-1]);
        #pragma unroll
        for (int m = 0; m < 8; ++m) sdat[slotf(tid + 512*m)] = v[m];
    }
    __syncthreads();                       // B1: strided init write -> s512 reads

    if (tid == 0){
        int a = 8192, b = -1, c = 8192, d = -1;
        for (int w = 0; w < 8; ++w){
            a = min(a, sred[w][0]); b = max(b, sred[w][1]);
            c = min(c, sred[w][2]); d = max(d, sred[w][3]);
        }
        int fr  = (a == 8192) ? 0 : a;       // empty-mask fallback per reference
        int lr_ = (b < 0) ? 8191 : b;
        int fi  = (c == 8192) ? 0 : c;
        int li_ = (d < 0) ? 8191 : d;
        s_first = min(fr, fi);
        s_last  = max(lr_, li_);
    }

    fwd_stage8<512>(sdat, tid);
    // no barrier: s512 -> s64 handoff is wave-local
    fwd_stage8<64 >(sdat, tid);
    __syncthreads();                       // B2: s64 writes -> middle PARTNER reads

    // ---------- Middle: fwd L=8 (regs) + Hilbert Z->C pairing + inv L=8 (regs) ----------
    {
        const int s  = rev3(tid);            // own 8 freqs: k = a*512 + s
        const int sp = (512 - s) & 511;      // partner digit-group
        const int tp = rev3(sp);
        cpx va[8], vb[8];
        #pragma unroll
        for (int a = 0; a < 8; ++a) va[a] = sdat[slotf(8*tid + a)];
        #pragma unroll
        for (int a = 0; a < 8; ++a) vb[a] = sdat[slotf(8*tp  + a)];
        __syncthreads();                     // B3: all reads before any writes
        dft8_fwd(va);
        dft8_fwd(vb);
        if (tid == 0){
            s_mean = (va[0].x + va[0].y) * (1.0f/8192.0f);   // Z[0] -> mean(x)
            #pragma unroll
            for (int i = 0; i < 8; ++i) vb[i] = va[(i + 1) & 7];  // kc=(8-a)*512 fix
        }
        cpx es = twf((float)s * (1.0f/8192.0f));
        // W16[a] = e^{2 pi i a/16}
        const float W16c[8] = {1.f, 0.92387953251f, 0.70710678119f, 0.38268343236f,
                               0.f, -0.38268343236f, -0.70710678119f, -0.92387953251f};
        const float W16s[8] = {0.f, 0.38268343236f, 0.70710678119f, 0.92387953251f,
                               1.f, 0.92387953251f, 0.70710678119f, 0.38268343236f};
        cpx C[8];
        #pragma unroll
        for (int a = 0; a < 8; ++a){
            cpx w  = cmul(make_float2(W16c[a], W16s[a]), es);  // e^{+i th}, th=2pi k/8192
            cpx wc = make_float2(w.x, -w.y);
            cpx Zb = vb[7 - a];                                // Z[4096-k]
            cpx E  = make_float2(0.5f*(va[a].x + Zb.x), 0.5f*(va[a].y - Zb.y));
            cpx D  = make_float2(0.5f*(va[a].x - Zb.x), 0.5f*(va[a].y + Zb.y));
            C[a] = csub(cmul(wc, D), cmul(w, E));
        }
        if (tid == 0) C[0] = make_float2(0.f, 0.f);            // H[0] = 0
        dft8_inv(C);
        #pragma unroll
        for (int a = 0; a < 8; ++a) sdat[slotf(8*tid + a)] = C[a];
    }
    // no barrier: middle write -> inv64 handoff is wave-local
    inv_stage8<64 >(sdat, tid);
    // no barrier: inv64 -> inv512 handoff is wave-local
    inv_stage8<512>(sdat, tid);
    __syncthreads();                       // B4: inv512 writes -> final strided reads

    // ---------- Final inv L=4096 (regs) fused with epilogue ----------
    const int   first = s_first;
    const int   last  = s_last;
    const float mean  = s_mean;
    const float invM  = 1.0f/4096.0f;

    float acc = 0.f;
    cpx y[8];
    {
        #pragma unroll
        for (int m = 0; m < 8; ++m) y[m] = sdat[slotf(tid + 512*m)];
        cpx w[7];
        twiddle7((float)tid * (1.0f/4096.0f), w);
        #pragma unroll
        for (int m = 1; m < 8; ++m) y[m] = cmul(y[m], w[m-1]);
        dft8_inv(y);
    }
    #pragma unroll
    for (int m = 0; m < 8; ++m){
        int tt = tid + 512*m;                  // c[tt] = h[2tt] + i h[2tt+1]
        float pi0 = y[m].x * invM, pi1 = y[m].y * invM;
        float pr0 = zv[m].x - mean, pr1 = zv[m].y - mean;
        int n = 2 * tt;
        {
            float dr = pr0 - lrv[m].x, di = pi0 - liv[m].x;
            acc = fmaf(dr, dr, acc);
            acc = fmaf(di, di, acc);
            float dint = fmaf(pr0, pr0, pi0*pi0) - fmaf(lrv[m].x, lrv[m].x, liv[m].x*liv[m].x);
            acc = fmaf(dint, dint, acc);
            if (n >= first && n < last){
                float dph = fast_atan2(pi0, pr0) - fast_atan2(liv[m].x, lrv[m].x);
                acc = fmaf(dph, dph, acc);
            }
        }
        {
            float dr = pr1 - lrv[m].y, di = pi1 - liv[m].y;
            acc = fmaf(dr, dr, acc);
            acc = fmaf(di, di, acc);
            float dint = fmaf(pr1, pr1, pi1*pi1) - fmaf(lrv[m].y, lrv[m].y, liv[m].y*liv[m].y);
            acc = fmaf(dint, dint, acc);
            if (n + 1 >= first && n + 1 < last){
                float dph = fast_atan2(pi1, pr1) - fast_atan2(liv[m].y, lrv[m].y);
                acc = fmaf(dph, dph, acc);
            }
        }
    }
    #pragma unroll
    for (int off = 32; off; off >>= 1) acc += __shfl_down(acc, off);
    if (lane == 0) swsum[wid] = acc;
    __syncthreads();
    if (tid == 0){
        float t = 0.f;
        for (int w = 0; w < 8; ++w) t += swsum[w];
        mse_per[row] = t * (1.0f/8192.0f) * 0.25f;   // /N /MSE_W_SUM
    }
}

__global__ __launch_bounds__(512) void pulse_final_kernel(
    const float* __restrict__ mse_per, float* __restrict__ out)
{
    const int tid = threadIdx.x;
    double v = 0.0;
    if (tid < NROWS) v = (double)(NROWS - tid) * (double)mse_per[tid];
    #pragma unroll
    for (int off = 32; off; off >>= 1) v += __shfl_down(v, off);
    __shared__ double lds[8];
    const int lane = tid & 63, wid = tid >> 6;
    if (lane == 0) lds[wid] = v;
    __syncthreads();
    if (tid == 0){
        double t = 0.0;
        for (int i = 0; i < 8; ++i) t += lds[i];
        out[0] = (float)(t / (double)NROWS);
    }
}

extern "C" void kernel_launch(void* const* d_in, const int* in_sizes, int n_in,
                              void* d_out, int out_size, void* d_ws, size_t ws_size,
                              hipStream_t stream) {
    const float* pred  = (const float*)d_in[0];   // (512, 8192)  f32
    const float* label = (const float*)d_in[1];   // (512, 16384) f32
    float* mse_per = (float*)d_ws;                // 512 floats scratch
    float* out     = (float*)d_out;               // 1 float

    pulse_row_kernel<<<NROWS, THREADS, 0, stream>>>(pred, label, mse_per);
    pulse_final_kernel<<<1, 512, 0, stream>>>(mse_per, out);
}

// Round 12
// 28.110 us; speedup vs baseline: 1.5618x; 1.5618x over previous
//
#include <hip/hip_runtime.h>

#define NROWS   512
#define THREADS 512
#define PULSE_THR 0.01f

typedef float2 cpx;

__device__ __forceinline__ cpx cadd(cpx a, cpx b){ return make_float2(a.x+b.x, a.y+b.y); }
__device__ __forceinline__ cpx csub(cpx a, cpx b){ return make_float2(a.x-b.x, a.y-b.y); }
__device__ __forceinline__ cpx cmul(cpx a, cpx b){
    return make_float2(fmaf(a.x, b.x, -(a.y*b.y)), fmaf(a.x, b.y, a.y*b.x));
}
__device__ __forceinline__ cpx cmuli(cpx a){ return make_float2(-a.y, a.x); }   // i*a
// e^{2*pi*i*rev} via native v_sin/v_cos (argument in revolutions)
__device__ __forceinline__ cpx twf(float rev){
    return make_float2(__builtin_amdgcn_cosf(rev), __builtin_amdgcn_sinf(rev));
}
// LDS slot swizzle: fold bits 4-11 into 0-3 to spread strided accesses.
// Only bits 0-3 change -> preserves 64-element region disjointness (barrier proof).
__device__ __forceinline__ int slotf(int e){ return e ^ ((e >> 4) & 15) ^ ((e >> 8) & 15); }
// base-8 digit reversal of a 9-bit index (3 digits) — involution
__device__ __forceinline__ int rev3(int t){ return ((t & 7) << 6) | (t & 0x38) | (t >> 6); }

// fast atan2: octant reduction + poly, |err| ~1e-5 rad
__device__ __forceinline__ float fast_atan2(float y, float x){
    float ax = fabsf(x), ay = fabsf(y);
    float mx = fmaxf(ax, ay), mn = fminf(ax, ay);
    float a  = mn * __builtin_amdgcn_rcpf(mx);
    if (mx == 0.0f) a = 0.0f;
    float s = a * a;
    float p = fmaf(s, fmaf(s, fmaf(s, fmaf(s, 0.0208351f, -0.085133f),
                                   0.180141f), -0.3302995f), 0.9998660f);
    p = p * a;
    if (ay > ax)   p = 1.57079632679f - p;
    if (x < 0.0f)  p = 3.14159265359f - p;
    return (y < 0.0f) ? -p : p;
}

// short-chain twiddle set: 3 independent sincos (TRANS pipe) + depth-2 cmuls
__device__ __forceinline__ void twiddle7(float sj_L, cpx* w){
    w[0] = twf(sj_L);                 // w1
    w[1] = twf(2.0f * sj_L);          // w2
    w[3] = twf(4.0f * sj_L);          // w4
    w[2] = cmul(w[0], w[1]);          // w3
    w[4] = cmul(w[0], w[3]);          // w5
    w[5] = cmul(w[1], w[3]);          // w6
    w[6] = cmul(w[2], w[3]);          // w7
}

// 8-point DFT, natural order in/out, W8 = e^{-2pi i/8}  (forward)
__device__ __forceinline__ void dft8_fwd(cpx* x){
    const float S = 0.70710678118654752f;
    cpx a0=cadd(x[0],x[4]), a1=cadd(x[1],x[5]), a2=cadd(x[2],x[6]), a3=cadd(x[3],x[7]);
    cpx b0=csub(x[0],x[4]), b1=csub(x[1],x[5]), b2=csub(x[2],x[6]), b3=csub(x[3],x[7]);
    cpx c0=cadd(a0,a2), c1=csub(a0,a2), c2=cadd(a1,a3), c3=csub(a1,a3);
    x[0]=cadd(c0,c2);
    x[4]=csub(c0,c2);
    x[2]=csub(c1,cmuli(c3));
    x[6]=cadd(c1,cmuli(c3));
    cpx t1 = make_float2(S*(b1.x+b1.y), S*(b1.y-b1.x));    // b1*W8
    cpx t2 = make_float2(b2.y, -b2.x);                     // b2*W8^2 = -i b2
    cpx t3 = make_float2(S*(b3.y-b3.x), -S*(b3.x+b3.y));   // b3*W8^3
    cpx d0=cadd(b0,t2), d1=csub(b0,t2), d2=cadd(t1,t3), d3=csub(t1,t3);
    x[1]=cadd(d0,d2);
    x[5]=csub(d0,d2);
    x[3]=csub(d1,cmuli(d3));
    x[7]=cadd(d1,cmuli(d3));
}
// 8-point inverse DFT (unnormalized), conj twiddles
__device__ __forceinline__ void dft8_inv(cpx* x){
    const float S = 0.70710678118654752f;
    cpx a0=cadd(x[0],x[4]), a1=cadd(x[1],x[5]), a2=cadd(x[2],x[6]), a3=cadd(x[3],x[7]);
    cpx b0=csub(x[0],x[4]), b1=csub(x[1],x[5]), b2=csub(x[2],x[6]), b3=csub(x[3],x[7]);
    cpx c0=cadd(a0,a2), c1=csub(a0,a2), c2=cadd(a1,a3), c3=csub(a1,a3);
    x[0]=cadd(c0,c2);
    x[4]=csub(c0,c2);
    x[2]=cadd(c1,cmuli(c3));
    x[6]=csub(c1,cmuli(c3));
    cpx t1 = make_float2(S*(b1.x-b1.y), S*(b1.y+b1.x));    // b1*conj(W8)
    cpx t2 = make_float2(-b2.y, b2.x);                     // +i b2
    cpx t3 = make_float2(-S*(b3.x+b3.y), S*(b3.x-b3.y));   // b3*conj(W8)^3
    cpx d0=cadd(b0,t2), d1=csub(b0,t2), d2=cadd(t1,t3), d3=csub(t1,t3);
    x[1]=cadd(d0,d2);
    x[5]=csub(d0,d2);
    x[3]=cadd(d1,cmuli(d3));
    x[7]=csub(d1,cmuli(d3));
}

// forward DIF radix-8 LDS stage
template<int L>
__device__ __forceinline__ void fwd_stage8(cpx* sd, int tid){
    constexpr int q = L / 8;
    const int j    = tid & (q - 1);
    const int base = ((tid & ~(q - 1)) << 3) + j;
    cpx v[8];
    #pragma unroll
    for (int m = 0; m < 8; ++m) v[m] = sd[slotf(base + m*q)];
    cpx w[7];
    twiddle7(-(float)j * (1.0f/(float)L), w);
    dft8_fwd(v);
    #pragma unroll
    for (int m = 1; m < 8; ++m) v[m] = cmul(v[m], w[m-1]);
    #pragma unroll
    for (int m = 0; m < 8; ++m) sd[slotf(base + m*q)] = v[m];
}
// inverse DIT radix-8 LDS stage
template<int L>
__device__ __forceinline__ void inv_stage8(cpx* sd, int tid){
    constexpr int q = L / 8;
    const int j    = tid & (q - 1);
    const int base = ((tid & ~(q - 1)) << 3) + j;
    cpx v[8];
    #pragma unroll
    for (int m = 0; m < 8; ++m) v[m] = sd[slotf(base + m*q)];
    cpx w[7];
    twiddle7((float)j * (1.0f/(float)L), w);
    #pragma unroll
    for (int m = 1; m < 8; ++m) v[m] = cmul(v[m], w[m-1]);
    dft8_inv(v);
    #pragma unroll
    for (int m = 0; m < 8; ++m) sd[slotf(base + m*q)] = v[m];
}

// init stage: z (regs) -> sd, fused fwd L=4096
__device__ __forceinline__ void init_stage(cpx* sd, const cpx* zv, int tid){
    cpx v[8];
    #pragma unroll
    for (int m = 0; m < 8; ++m) v[m] = zv[m];
    cpx w[7];
    twiddle7(-(float)tid * (1.0f/4096.0f), w);
    dft8_fwd(v);
    #pragma unroll
    for (int m = 1; m < 8; ++m) v[m] = cmul(v[m], w[m-1]);
    #pragma unroll
    for (int m = 0; m < 8; ++m) sd[slotf(tid + 512*m)] = v[m];
}

// middle processing after the two fwd stages: va/vb already read from LDS.
// Computes Hilbert Z->C pairing and writes inverse-L8 result back to sd.
__device__ __forceinline__ void middle_process(cpx* va, cpx* vb, cpx* sd,
                                               int s, int tid, float* s_mean){
    dft8_fwd(va);
    dft8_fwd(vb);
    if (tid == 0){
        *s_mean = (va[0].x + va[0].y) * (1.0f/8192.0f);   // Z[0] -> mean(x)
        #pragma unroll
        for (int i = 0; i < 8; ++i) vb[i] = va[(i + 1) & 7];  // kc=(8-a)*512 fix
    }
    cpx es = twf((float)s * (1.0f/8192.0f));
    const float W16c[8] = {1.f, 0.92387953251f, 0.70710678119f, 0.38268343236f,
                           0.f, -0.38268343236f, -0.70710678119f, -0.92387953251f};
    const float W16s[8] = {0.f, 0.38268343236f, 0.70710678119f, 0.92387953251f,
                           1.f, 0.92387953251f, 0.70710678119f, 0.38268343236f};
    cpx C[8];
    #pragma unroll
    for (int a = 0; a < 8; ++a){
        cpx w  = cmul(make_float2(W16c[a], W16s[a]), es);  // e^{+i th}, th=2pi k/8192
        cpx wc = make_float2(w.x, -w.y);
        cpx Zb = vb[7 - a];                                // Z[4096-k]
        cpx E  = make_float2(0.5f*(va[a].x + Zb.x), 0.5f*(va[a].y - Zb.y));
        cpx D  = make_float2(0.5f*(va[a].x - Zb.x), 0.5f*(va[a].y + Zb.y));
        C[a] = csub(cmul(wc, D), cmul(w, E));
    }
    if (tid == 0) C[0] = make_float2(0.f, 0.f);            // H[0] = 0
    dft8_inv(C);
    #pragma unroll
    for (int a = 0; a < 8; ++a) sd[slotf(8*tid + a)] = C[a];
}

// epilogue for one row: final inv L=4096 from sd + loss accumulation
__device__ __forceinline__ float epilogue_acc(const float* lab_r, const float* lab_i,
                                              cpx* sd, const cpx* zv, float mean,
                                              int first, int last, int tid){
    const float invM = 1.0f/4096.0f;
    const float2* lr2 = (const float2*)lab_r;
    const float2* li2 = (const float2*)lab_i;
    float2 lrv[8], liv[8];
    #pragma unroll
    for (int m = 0; m < 8; ++m){
        lrv[m] = lr2[tid + 512*m];
        liv[m] = li2[tid + 512*m];
    }
    cpx y[8];
    #pragma unroll
    for (int m = 0; m < 8; ++m) y[m] = sd[slotf(tid + 512*m)];
    cpx w[7];
    twiddle7((float)tid * (1.0f/4096.0f), w);
    #pragma unroll
    for (int m = 1; m < 8; ++m) y[m] = cmul(y[m], w[m-1]);
    dft8_inv(y);
    float acc = 0.f;
    #pragma unroll
    for (int m = 0; m < 8; ++m){
        int n = 2 * (tid + 512*m);
        float pi0 = y[m].x * invM, pi1 = y[m].y * invM;
        float pr0 = zv[m].x - mean, pr1 = zv[m].y - mean;
        {
            float dr = pr0 - lrv[m].x, di = pi0 - liv[m].x;
            acc = fmaf(dr, dr, acc);
            acc = fmaf(di, di, acc);
            float dint = fmaf(pr0, pr0, pi0*pi0) - fmaf(lrv[m].x, lrv[m].x, liv[m].x*liv[m].x);
            acc = fmaf(dint, dint, acc);
            if (n >= first && n < last){
                float dph = fast_atan2(pi0, pr0) - fast_atan2(liv[m].x, lrv[m].x);
                acc = fmaf(dph, dph, acc);
            }
        }
        {
            float dr = pr1 - lrv[m].y, di = pi1 - liv[m].y;
            acc = fmaf(dr, dr, acc);
            acc = fmaf(di, di, acc);
            float dint = fmaf(pr1, pr1, pi1*pi1) - fmaf(lrv[m].y, lrv[m].y, liv[m].y*liv[m].y);
            acc = fmaf(dint, dint, acc);
            if (n + 1 >= first && n + 1 < last){
                float dph = fast_atan2(pi1, pr1) - fast_atan2(liv[m].y, lrv[m].y);
                acc = fmaf(dph, dph, acc);
            }
        }
    }
    return acc;
}

// Two rows per block: every barrier-separated phase does row A then row B.
// Barriers per row halve; each wave carries two independent dep chains.
// 1 block/CU (grid 256) -> 2 waves/SIMD -> VGPR budget 256 (no spill risk
// at the middle section's ~140-VGPR peak). LDS: 2 x 32 KB + small.
__global__ __launch_bounds__(THREADS, 2) void pulse_row2_kernel(
    const float* __restrict__ pred,
    const float* __restrict__ label,
    float* __restrict__ mse_per)
{
    __shared__ cpx   sA[4096];             // 32 KB
    __shared__ cpx   sB[4096];             // 32 KB
    __shared__ int   sred[8][8];
    __shared__ float swsum[8][2];
    __shared__ int   s_firstA, s_lastA, s_firstB, s_lastB;
    __shared__ float s_meanA, s_meanB;

    const int rowA = blockIdx.x * 2;
    const int rowB = rowA + 1;
    const int tid  = threadIdx.x;
    const int lane = tid & 63;
    const int wid  = tid >> 6;

    const float* labA_r = label + (size_t)rowA * 16384;
    const float* labA_i = labA_r + 8192;
    const float* labB_r = label + (size_t)rowB * 16384;
    const float* labB_i = labB_r + 8192;

    // ---------- Phase 0: pulse-window scan for BOTH rows ----------
    int minrA = 8192, maxrA = -1, miniA = 8192, maxiA = -1;
    int minrB = 8192, maxrB = -1, miniB = 8192, maxiB = -1;
    {
        const float4* lrA = (const float4*)labA_r;
        const float4* liA = (const float4*)labA_i;
        const float4* lrB = (const float4*)labB_r;
        const float4* liB = (const float4*)labB_i;
        #pragma unroll
        for (int it = 0; it < 4; ++it){
            int idx = tid + THREADS * it;
            int n0 = idx << 2;
            float4 a = lrA[idx], b = liA[idx];
            float4 c = lrB[idx], d = liB[idx];
            if (fabsf(a.x) > PULSE_THR){ minrA = min(minrA, n0);   maxrA = max(maxrA, n0);   }
            if (fabsf(a.y) > PULSE_THR){ minrA = min(minrA, n0+1); maxrA = max(maxrA, n0+1); }
            if (fabsf(a.z) > PULSE_THR){ minrA = min(minrA, n0+2); maxrA = max(maxrA, n0+2); }
            if (fabsf(a.w) > PULSE_THR){ minrA = min(minrA, n0+3); maxrA = max(maxrA, n0+3); }
            if (fabsf(b.x) > PULSE_THR){ miniA = min(miniA, n0);   maxiA = max(maxiA, n0);   }
            if (fabsf(b.y) > PULSE_THR){ miniA = min(miniA, n0+1); maxiA = max(maxiA, n0+1); }
            if (fabsf(b.z) > PULSE_THR){ miniA = min(miniA, n0+2); maxiA = max(maxiA, n0+2); }
            if (fabsf(b.w) > PULSE_THR){ miniA = min(miniA, n0+3); maxiA = max(maxiA, n0+3); }
            if (fabsf(c.x) > PULSE_THR){ minrB = min(minrB, n0);   maxrB = max(maxrB, n0);   }
            if (fabsf(c.y) > PULSE_THR){ minrB = min(minrB, n0+1); maxrB = max(maxrB, n0+1); }
            if (fabsf(c.z) > PULSE_THR){ minrB = min(minrB, n0+2); maxrB = max(maxrB, n0+2); }
            if (fabsf(c.w) > PULSE_THR){ minrB = min(minrB, n0+3); maxrB = max(maxrB, n0+3); }
            if (fabsf(d.x) > PULSE_THR){ miniB = min(miniB, n0);   maxiB = max(maxiB, n0);   }
            if (fabsf(d.y) > PULSE_THR){ miniB = min(miniB, n0+1); maxiB = max(maxiB, n0+1); }
            if (fabsf(d.z) > PULSE_THR){ miniB = min(miniB, n0+2); maxiB = max(maxiB, n0+2); }
            if (fabsf(d.w) > PULSE_THR){ miniB = min(miniB, n0+3); maxiB = max(maxiB, n0+3); }
        }
    }
    #pragma unroll
    for (int off = 32; off; off >>= 1){
        minrA = min(minrA, __shfl_down(minrA, off));
        maxrA = max(maxrA, __shfl_down(maxrA, off));
        miniA = min(miniA, __shfl_down(miniA, off));
        maxiA = max(maxiA, __shfl_down(maxiA, off));
        minrB = min(minrB, __shfl_down(minrB, off));
        maxrB = max(maxrB, __shfl_down(maxrB, off));
        miniB = min(miniB, __shfl_down(miniB, off));
        maxiB = max(maxiB, __shfl_down(maxiB, off));
    }
    if (lane == 0){
        sred[wid][0]=minrA; sred[wid][1]=maxrA; sred[wid][2]=miniA; sred[wid][3]=maxiA;
        sred[wid][4]=minrB; sred[wid][5]=maxrB; sred[wid][6]=miniB; sred[wid][7]=maxiB;
    }

    // ---------- Load z for both rows (kept in regs) + init stages ----------
    const float2* zinA = (const float2*)(pred + (size_t)rowA * 8192);
    const float2* zinB = (const float2*)(pred + (size_t)rowB * 8192);
    cpx zvA[8], zvB[8];
    #pragma unroll
    for (int u = 0; u < 8; ++u) zvA[u] = zinA[tid + THREADS * u];
    #pragma unroll
    for (int u = 0; u < 8; ++u) zvB[u] = zinB[tid + THREADS * u];
    init_stage(sA, zvA, tid);
    init_stage(sB, zvB, tid);
    __syncthreads();                       // B1 (both rows)

    if (tid == 0){
        int a = 8192, b = -1, c = 8192, d = -1;
        int e = 8192, f = -1, g = 8192, h = -1;
        for (int w = 0; w < 8; ++w){
            a = min(a, sred[w][0]); b = max(b, sred[w][1]);
            c = min(c, sred[w][2]); d = max(d, sred[w][3]);
            e = min(e, sred[w][4]); f = max(f, sred[w][5]);
            g = min(g, sred[w][6]); h = max(h, sred[w][7]);
        }
        int frA  = (a == 8192) ? 0 : a;
        int lrA_ = (b < 0) ? 8191 : b;
        int fiA  = (c == 8192) ? 0 : c;
        int liA_ = (d < 0) ? 8191 : d;
        s_firstA = min(frA, fiA);
        s_lastA  = max(lrA_, liA_);
        int frB  = (e == 8192) ? 0 : e;
        int lrB_ = (f < 0) ? 8191 : f;
        int fiB  = (g == 8192) ? 0 : g;
        int liB_ = (h < 0) ? 8191 : h;
        s_firstB = min(frB, fiB);
        s_lastB  = max(lrB_, liB_);
    }

    fwd_stage8<512>(sA, tid);
    fwd_stage8<512>(sB, tid);
    // no barrier: s512 -> s64 handoff is wave-local (per array)
    fwd_stage8<64 >(sA, tid);
    fwd_stage8<64 >(sB, tid);
    __syncthreads();                       // B2 (both rows)

    // ---------- Middle for both rows ----------
    {
        const int s  = rev3(tid);
        const int sp = (512 - s) & 511;
        const int tp = rev3(sp);
        cpx vaA[8], vbA[8], vaB[8], vbB[8];
        #pragma unroll
        for (int a = 0; a < 8; ++a) vaA[a] = sA[slotf(8*tid + a)];
        #pragma unroll
        for (int a = 0; a < 8; ++a) vbA[a] = sA[slotf(8*tp  + a)];
        #pragma unroll
        for (int a = 0; a < 8; ++a) vaB[a] = sB[slotf(8*tid + a)];
        #pragma unroll
        for (int a = 0; a < 8; ++a) vbB[a] = sB[slotf(8*tp  + a)];
        __syncthreads();                   // B3: all reads before any writes
        middle_process(vaA, vbA, sA, s, tid, &s_meanA);
        middle_process(vaB, vbB, sB, s, tid, &s_meanB);
    }
    // no barrier: middle write -> inv64 handoff is wave-local
    inv_stage8<64 >(sA, tid);
    inv_stage8<64 >(sB, tid);
    // no barrier: inv64 -> inv512 handoff is wave-local
    inv_stage8<512>(sA, tid);
    inv_stage8<512>(sB, tid);
    __syncthreads();                       // B4 (both rows)

    // ---------- Epilogues ----------
    float accA = epilogue_acc(labA_r, labA_i, sA, zvA, s_meanA, s_firstA, s_lastA, tid);
    float accB = epilogue_acc(labB_r, labB_i, sB, zvB, s_meanB, s_firstB, s_lastB, tid);

    #pragma unroll
    for (int off = 32; off; off >>= 1){
        accA += __shfl_down(accA, off);
        accB += __shfl_down(accB, off);
    }
    if (lane == 0){ swsum[wid][0] = accA; swsum[wid][1] = accB; }
    __syncthreads();
    if (tid == 0){
        float tA = 0.f, tB = 0.f;
        for (int w = 0; w < 8; ++w){ tA += swsum[w][0]; tB += swsum[w][1]; }
        mse_per[rowA] = tA * (1.0f/8192.0f) * 0.25f;   // /N /MSE_W_SUM
        mse_per[rowB] = tB * (1.0f/8192.0f) * 0.25f;
    }
}

__global__ __launch_bounds__(512) void pulse_final_kernel(
    const float* __restrict__ mse_per, float* __restrict__ out)
{
    const int tid = threadIdx.x;
    double v = 0.0;
    if (tid < NROWS) v = (double)(NROWS - tid) * (double)mse_per[tid];
    #pragma unroll
    for (int off = 32; off; off >>= 1) v += __shfl_down(v, off);
    __shared__ double lds[8];
    const int lane = tid & 63, wid = tid >> 6;
    if (lane == 0) lds[wid] = v;
    __syncthreads();
    if (tid == 0){
        double t = 0.0;
        for (int i = 0; i < 8; ++i) t += lds[i];
        out[0] = (float)(t / (double)NROWS);
    }
}

extern "C" void kernel_launch(void* const* d_in, const int* in_sizes, int n_in,
                              void* d_out, int out_size, void* d_ws, size_t ws_size,
                              hipStream_t stream) {
    const float* pred  = (const float*)d_in[0];   // (512, 8192)  f32
    const float* label = (const float*)d_in[1];   // (512, 16384) f32
    float* mse_per = (float*)d_ws;                // 512 floats scratch
    float* out     = (float*)d_out;               // 1 float

    pulse_row2_kernel<<<NROWS/2, THREADS, 0, stream>>>(pred, label, mse_per);
    pulse_final_kernel<<<1, 512, 0, stream>>>(mse_per, out);
}

// Round 13
// 25.968 us; speedup vs baseline: 1.6906x; 1.0825x over previous
//
#include <hip/hip_runtime.h>

#define NROWS   512
#define THREADS 512
#define PULSE_THR 0.01f

typedef float2 cpx;

__device__ __forceinline__ cpx cadd(cpx a, cpx b){ return make_float2(a.x+b.x, a.y+b.y); }
__device__ __forceinline__ cpx csub(cpx a, cpx b){ return make_float2(a.x-b.x, a.y-b.y); }
__device__ __forceinline__ cpx cmul(cpx a, cpx b){
    return make_float2(fmaf(a.x, b.x, -(a.y*b.y)), fmaf(a.x, b.y, a.y*b.x));
}
__device__ __forceinline__ cpx cmuli(cpx a){ return make_float2(-a.y, a.x); }   // i*a
// e^{2*pi*i*rev} via native v_sin/v_cos (argument in revolutions)
__device__ __forceinline__ cpx twf(float rev){
    return make_float2(__builtin_amdgcn_cosf(rev), __builtin_amdgcn_sinf(rev));
}
// LDS slot swizzle: fold bits 4-11 into 0-3 to spread strided accesses.
// Only bits 0-3 change -> preserves 64-element region disjointness (barrier proof).
__device__ __forceinline__ int slotf(int e){ return e ^ ((e >> 4) & 15) ^ ((e >> 8) & 15); }
// base-8 digit reversal of a 9-bit index (3 digits) — involution
__device__ __forceinline__ int rev3(int t){ return ((t & 7) << 6) | (t & 0x38) | (t >> 6); }

// fast atan2: octant reduction + poly, |err| ~1e-5 rad
__device__ __forceinline__ float fast_atan2(float y, float x){
    float ax = fabsf(x), ay = fabsf(y);
    float mx = fmaxf(ax, ay), mn = fminf(ax, ay);
    float a  = mn * __builtin_amdgcn_rcpf(mx);
    if (mx == 0.0f) a = 0.0f;
    float s = a * a;
    float p = fmaf(s, fmaf(s, fmaf(s, fmaf(s, 0.0208351f, -0.085133f),
                                   0.180141f), -0.3302995f), 0.9998660f);
    p = p * a;
    if (ay > ax)   p = 1.57079632679f - p;
    if (x < 0.0f)  p = 3.14159265359f - p;
    return (y < 0.0f) ? -p : p;
}

// short-chain twiddle set: 3 independent sincos (TRANS pipe) + depth-2 cmuls
__device__ __forceinline__ void twiddle7(float sj_L, cpx* w){
    w[0] = twf(sj_L);                 // w1
    w[1] = twf(2.0f * sj_L);          // w2
    w[3] = twf(4.0f * sj_L);          // w4
    w[2] = cmul(w[0], w[1]);          // w3
    w[4] = cmul(w[0], w[3]);          // w5
    w[5] = cmul(w[1], w[3]);          // w6
    w[6] = cmul(w[2], w[3]);          // w7
}

// 8-point DFT, natural order in/out, W8 = e^{-2pi i/8}  (forward)
__device__ __forceinline__ void dft8_fwd(cpx* x){
    const float S = 0.70710678118654752f;
    cpx a0=cadd(x[0],x[4]), a1=cadd(x[1],x[5]), a2=cadd(x[2],x[6]), a3=cadd(x[3],x[7]);
    cpx b0=csub(x[0],x[4]), b1=csub(x[1],x[5]), b2=csub(x[2],x[6]), b3=csub(x[3],x[7]);
    cpx c0=cadd(a0,a2), c1=csub(a0,a2), c2=cadd(a1,a3), c3=csub(a1,a3);
    x[0]=cadd(c0,c2);
    x[4]=csub(c0,c2);
    x[2]=csub(c1,cmuli(c3));
    x[6]=cadd(c1,cmuli(c3));
    cpx t1 = make_float2(S*(b1.x+b1.y), S*(b1.y-b1.x));    // b1*W8
    cpx t2 = make_float2(b2.y, -b2.x);                     // b2*W8^2 = -i b2
    cpx t3 = make_float2(S*(b3.y-b3.x), -S*(b3.x+b3.y));   // b3*W8^3
    cpx d0=cadd(b0,t2), d1=csub(b0,t2), d2=cadd(t1,t3), d3=csub(t1,t3);
    x[1]=cadd(d0,d2);
    x[5]=csub(d0,d2);
    x[3]=csub(d1,cmuli(d3));
    x[7]=cadd(d1,cmuli(d3));
}
// 8-point inverse DFT (unnormalized), conj twiddles
__device__ __forceinline__ void dft8_inv(cpx* x){
    const float S = 0.70710678118654752f;
    cpx a0=cadd(x[0],x[4]), a1=cadd(x[1],x[5]), a2=cadd(x[2],x[6]), a3=cadd(x[3],x[7]);
    cpx b0=csub(x[0],x[4]), b1=csub(x[1],x[5]), b2=csub(x[2],x[6]), b3=csub(x[3],x[7]);
    cpx c0=cadd(a0,a2), c1=csub(a0,a2), c2=cadd(a1,a3), c3=csub(a1,a3);
    x[0]=cadd(c0,c2);
    x[4]=csub(c0,c2);
    x[2]=cadd(c1,cmuli(c3));
    x[6]=csub(c1,cmuli(c3));
    cpx t1 = make_float2(S*(b1.x-b1.y), S*(b1.y+b1.x));    // b1*conj(W8)
    cpx t2 = make_float2(-b2.y, b2.x);                     // +i b2
    cpx t3 = make_float2(-S*(b3.x+b3.y), S*(b3.x-b3.y));   // b3*conj(W8)^3
    cpx d0=cadd(b0,t2), d1=csub(b0,t2), d2=cadd(t1,t3), d3=csub(t1,t3);
    x[1]=cadd(d0,d2);
    x[5]=csub(d0,d2);
    x[3]=cadd(d1,cmuli(d3));
    x[7]=csub(d1,cmuli(d3));
}

// forward DIF radix-8 LDS stage
template<int L>
__device__ __forceinline__ void fwd_stage8(cpx* sd, int tid){
    constexpr int q = L / 8;
    const int j    = tid & (q - 1);
    const int base = ((tid & ~(q - 1)) << 3) + j;
    cpx v[8];
    #pragma unroll
    for (int m = 0; m < 8; ++m) v[m] = sd[slotf(base + m*q)];
    cpx w[7];
    twiddle7(-(float)j * (1.0f/(float)L), w);
    dft8_fwd(v);
    #pragma unroll
    for (int m = 1; m < 8; ++m) v[m] = cmul(v[m], w[m-1]);
    #pragma unroll
    for (int m = 0; m < 8; ++m) sd[slotf(base + m*q)] = v[m];
}
// inverse DIT radix-8 LDS stage
template<int L>
__device__ __forceinline__ void inv_stage8(cpx* sd, int tid){
    constexpr int q = L / 8;
    const int j    = tid & (q - 1);
    const int base = ((tid & ~(q - 1)) << 3) + j;
    cpx v[8];
    #pragma unroll
    for (int m = 0; m < 8; ++m) v[m] = sd[slotf(base + m*q)];
    cpx w[7];
    twiddle7((float)j * (1.0f/(float)L), w);
    #pragma unroll
    for (int m = 1; m < 8; ++m) v[m] = cmul(v[m], w[m-1]);
    dft8_inv(v);
    #pragma unroll
    for (int m = 0; m < 8; ++m) sd[slotf(base + m*q)] = v[m];
}

// Barrier-elision proof sketch (8 waves x 64 lanes, element regions of sdat):
//  stage<512>: wave w owns exactly [w*512, w*512+512).
//  stage<64>:  thread block [(tid>>3)*64, +64) lies inside wave (tid>>6)'s region.
//  middle own: [8*tid, 8*tid+8) inside the same wave region.
//  => s512->s64, middle-write->inv64, inv64->inv512 are wave-local handoffs
//     (per-wave DS ops in order; cross-wave regions disjoint) — no barrier.
//  Barriers kept: init strided write -> s512; s64 -> middle PARTNER read;
//  middle reads -> writes; inv512 -> final strided read; y-read -> dph-write.

__global__ __launch_bounds__(THREADS, 4) void pulse_row_kernel(
    const float* __restrict__ pred,
    const float* __restrict__ label,
    float* __restrict__ mse_per)
{
    __shared__ cpx   sdat[4096];           // 32 KB; reused as float[8192] for dph^2
    __shared__ int   sred[8][4];
    __shared__ float swsum[8];
    __shared__ int   s_first, s_last;
    __shared__ float s_mean;

    const int row  = blockIdx.x;
    const int tid  = threadIdx.x;
    const int lane = tid & 63;
    const int wid  = tid >> 6;

    const float* lab_r = label + (size_t)row * 16384;
    const float* lab_i = lab_r + 8192;

    // ---------- Load z[t]=x[2t]+i x[2t+1] (kept in regs) + fused fwd L=4096 ----------
    const float2* zin = (const float2*)(pred + (size_t)row * 8192);
    cpx zv[8];
    #pragma unroll
    for (int u = 0; u < 8; ++u) zv[u] = zin[tid + THREADS * u];
    {
        cpx v[8];
        #pragma unroll
        for (int m = 0; m < 8; ++m) v[m] = zv[m];
        cpx w[7];
        twiddle7(-(float)tid * (1.0f/4096.0f), w);
        dft8_fwd(v);
        #pragma unroll
        for (int m = 1; m < 8; ++m) v[m] = cmul(v[m], w[m-1]);
        #pragma unroll
        for (int m = 0; m < 8; ++m) sdat[slotf(tid + 512*m)] = v[m];
    }
    __syncthreads();                       // B1: strided init write -> s512 reads

    fwd_stage8<512>(sdat, tid);
    // no barrier: s512 -> s64 handoff is wave-local
    fwd_stage8<64 >(sdat, tid);
    __syncthreads();                       // B2: s64 writes -> middle PARTNER reads

    // ---------- Middle: fwd L=8 (regs) + Hilbert Z->C pairing + inv L=8 (regs) ----------
    {
        const int s  = rev3(tid);            // own 8 freqs: k = a*512 + s
        const int sp = (512 - s) & 511;      // partner digit-group
        const int tp = rev3(sp);
        cpx va[8], vb[8];
        #pragma unroll
        for (int a = 0; a < 8; ++a) va[a] = sdat[slotf(8*tid + a)];
        #pragma unroll
        for (int a = 0; a < 8; ++a) vb[a] = sdat[slotf(8*tp  + a)];
        __syncthreads();                     // B3: all reads before any writes
        dft8_fwd(va);
        dft8_fwd(vb);
        if (tid == 0){
            s_mean = (va[0].x + va[0].y) * (1.0f/8192.0f);   // Z[0] -> mean(x)
            #pragma unroll
            for (int i = 0; i < 8; ++i) vb[i] = va[(i + 1) & 7];  // kc=(8-a)*512 fix
        }
        cpx es = twf((float)s * (1.0f/8192.0f));
        // W16[a] = e^{2 pi i a/16}
        const float W16c[8] = {1.f, 0.92387953251f, 0.70710678119f, 0.38268343236f,
                               0.f, -0.38268343236f, -0.70710678119f, -0.92387953251f};
        const float W16s[8] = {0.f, 0.38268343236f, 0.70710678119f, 0.92387953251f,
                               1.f, 0.92387953251f, 0.70710678119f, 0.38268343236f};
        cpx C[8];
        #pragma unroll
        for (int a = 0; a < 8; ++a){
            cpx w  = cmul(make_float2(W16c[a], W16s[a]), es);  // e^{+i th}, th=2pi k/8192
            cpx wc = make_float2(w.x, -w.y);
            cpx Zb = vb[7 - a];                                // Z[4096-k]
            cpx E  = make_float2(0.5f*(va[a].x + Zb.x), 0.5f*(va[a].y - Zb.y));
            cpx D  = make_float2(0.5f*(va[a].x - Zb.x), 0.5f*(va[a].y + Zb.y));
            C[a] = csub(cmul(wc, D), cmul(w, E));
        }
        if (tid == 0) C[0] = make_float2(0.f, 0.f);            // H[0] = 0
        dft8_inv(C);
        #pragma unroll
        for (int a = 0; a < 8; ++a) sdat[slotf(8*tid + a)] = C[a];
    }
    // no barrier: middle write -> inv64 handoff is wave-local
    inv_stage8<64 >(sdat, tid);
    // no barrier: inv64 -> inv512 handoff is wave-local
    inv_stage8<512>(sdat, tid);
    __syncthreads();                       // B4: inv512 writes -> final strided reads

    // ---------- Single-pass epilogue ----------
    const float invM  = 1.0f/4096.0f;
    const float2* lr2 = (const float2*)lab_r;
    const float2* li2 = (const float2*)lab_i;

    // (1) issue the ONLY label loads (VMEM in flight under y-compute)
    float2 lrv[8], liv[8];
    #pragma unroll
    for (int m = 0; m < 8; ++m){
        lrv[m] = lr2[tid + 512*m];
        liv[m] = li2[tid + 512*m];
    }

    // (2) final inverse stage in regs (hides label-load latency)
    cpx y[8];
    {
        #pragma unroll
        for (int m = 0; m < 8; ++m) y[m] = sdat[slotf(tid + 512*m)];
        cpx w[7];
        twiddle7((float)tid * (1.0f/4096.0f), w);
        #pragma unroll
        for (int m = 1; m < 8; ++m) y[m] = cmul(y[m], w[m-1]);
        dft8_inv(y);
    }
    __syncthreads();                       // B5: all y LDS reads done -> sdat reusable

    // (3) one pass: acc3 terms + unconditional dph^2 -> LDS + window trackers
    float* fp = (float*)sdat;              // 8192 floats, index = point n in [0,8192)
    const float mean = s_mean;
    float acc = 0.f;
    int minr = 8192, maxr = -1, mini = 8192, maxi = -1;
    #pragma unroll
    for (int m = 0; m < 8; ++m){
        int n = 2 * (tid + 512*m);
        float pi0 = y[m].x * invM, pi1 = y[m].y * invM;
        float pr0 = zv[m].x - mean, pr1 = zv[m].y - mean;
        float lr0 = lrv[m].x, li0 = liv[m].x;
        float lr1 = lrv[m].y, li1 = liv[m].y;
        {
            float dr = pr0 - lr0, di = pi0 - li0;
            acc = fmaf(dr, dr, acc);
            acc = fmaf(di, di, acc);
            float dint = fmaf(pr0, pr0, pi0*pi0) - fmaf(lr0, lr0, li0*li0);
            acc = fmaf(dint, dint, acc);
            float dph = fast_atan2(pi0, pr0) - fast_atan2(li0, lr0);
            fp[n] = dph * dph;
            if (fabsf(lr0) > PULSE_THR){ minr = min(minr, n); maxr = max(maxr, n); }
            if (fabsf(li0) > PULSE_THR){ mini = min(mini, n); maxi = max(maxi, n); }
        }
        {
            float dr = pr1 - lr1, di = pi1 - li1;
            acc = fmaf(dr, dr, acc);
            acc = fmaf(di, di, acc);
            float dint = fmaf(pr1, pr1, pi1*pi1) - fmaf(lr1, lr1, li1*li1);
            acc = fmaf(dint, dint, acc);
            float dph = fast_atan2(pi1, pr1) - fast_atan2(li1, lr1);
            fp[n + 1] = dph * dph;
            if (fabsf(lr1) > PULSE_THR){ minr = min(minr, n+1); maxr = max(maxr, n+1); }
            if (fabsf(li1) > PULSE_THR){ mini = min(mini, n+1); maxi = max(maxi, n+1); }
        }
    }

    // (4) window combine
    #pragma unroll
    for (int off = 32; off; off >>= 1){
        minr = min(minr, __shfl_down(minr, off));
        maxr = max(maxr, __shfl_down(maxr, off));
        mini = min(mini, __shfl_down(mini, off));
        maxi = max(maxi, __shfl_down(maxi, off));
    }
    if (lane == 0){ sred[wid][0]=minr; sred[wid][1]=maxr; sred[wid][2]=mini; sred[wid][3]=maxi; }
    __syncthreads();                       // B6: sred + dph writes -> reads
    if (tid == 0){
        int a = 8192, b = -1, c = 8192, d = -1;
        for (int w = 0; w < 8; ++w){
            a = min(a, sred[w][0]); b = max(b, sred[w][1]);
            c = min(c, sred[w][2]); d = max(d, sred[w][3]);
        }
        int fr  = (a == 8192) ? 0 : a;       // empty-mask fallback per reference
        int lr_ = (b < 0) ? 8191 : b;
        int fi  = (c == 8192) ? 0 : c;
        int li_ = (d < 0) ? 8191 : d;
        s_first = min(fr, fi);
        s_last  = max(lr_, li_);
    }
    __syncthreads();                       // B7: window broadcast
    const int first = s_first;
    const int last  = s_last;

    // (5) gated phase sum from LDS-parked dph^2 (own values; float2 reads)
    #pragma unroll
    for (int m = 0; m < 8; ++m){
        int n = 2 * (tid + 512*m);
        float2 d2 = *(const float2*)&fp[n];
        if (n     >= first && n     < last) acc += d2.x;
        if (n + 1 >= first && n + 1 < last) acc += d2.y;
    }

    // (6) block reduce
    #pragma unroll
    for (int off = 32; off; off >>= 1) acc += __shfl_down(acc, off);
    if (lane == 0) swsum[wid] = acc;
    __syncthreads();                       // B8
    if (tid == 0){
        float t = 0.f;
        for (int w = 0; w < 8; ++w) t += swsum[w];
        mse_per[row] = t * (1.0f/8192.0f) * 0.25f;   // /N /MSE_W_SUM
    }
}

__global__ __launch_bounds__(512) void pulse_final_kernel(
    const float* __restrict__ mse_per, float* __restrict__ out)
{
    const int tid = threadIdx.x;
    double v = 0.0;
    if (tid < NROWS) v = (double)(NROWS - tid) * (double)mse_per[tid];
    #pragma unroll
    for (int off = 32; off; off >>= 1) v += __shfl_down(v, off);
    __shared__ double lds[8];
    const int lane = tid & 63, wid = tid >> 6;
    if (lane == 0) lds[wid] = v;
    __syncthreads();
    if (tid == 0){
        double t = 0.0;
        for (int i = 0; i < 8; ++i) t += lds[i];
        out[0] = (float)(t / (double)NROWS);
    }
}

extern "C" void kernel_launch(void* const* d_in, const int* in_sizes, int n_in,
                              void* d_out, int out_size, void* d_ws, size_t ws_size,
                              hipStream_t stream) {
    const float* pred  = (const float*)d_in[0];   // (512, 8192)  f32
    const float* label = (const float*)d_in[1];   // (512, 16384) f32
    float* mse_per = (float*)d_ws;                // 512 floats scratch
    float* out     = (float*)d_out;               // 1 float

    pulse_row_kernel<<<NROWS, THREADS, 0, stream>>>(pred, label, mse_per);
    pulse_final_kernel<<<1, 512, 0, stream>>>(mse_per, out);
}